// Round 15
// baseline (135.003 us; speedup 1.0000x reference)
//
#include <hip/hip_runtime.h>
#include <hip/hip_bf16.h>

#define IN_FEAT 4096
#define OUT_FEAT 4096
#define FP_FEAT 256
#define INT_FEAT 3840
#define TOKENS 4096
#define PACKED_W (INT_FEAT / 2)  // 1920

#define NT_I8 60          // int K-tiles (K=64 i8 each)
#define NT_ALL 68         // + 8 fp sub-tiles (K=32 bf16 each)

typedef __attribute__((ext_vector_type(8))) short short8;
typedef __attribute__((ext_vector_type(4))) float f32x4;
typedef __attribute__((ext_vector_type(4))) int   int32x4;

// workspace layout (bytes)
#define AQ8_OFF   0u
#define WB8_OFF   16777216u
#define AFP_OFF   33554432u
#define WFP_OFF   35651584u
#define SCALE_OFF 37748736u
#define ZERO_OFF  37765120u
#define WS_NEED   37781504u

// ------------------------------------------------- fused quantize + unpack ---
__global__ __launch_bounds__(256) void prep_kernel(
    const float* __restrict__ x,
    const int* __restrict__ int_idx_raw,
    const int* __restrict__ fp_idx_raw,
    const int* __restrict__ wpacked_raw,
    const float* __restrict__ fpw,
    const float* __restrict__ wscale,
    signed char* __restrict__ Aq8,
    __hip_bfloat16* __restrict__ Afp,
    signed char* __restrict__ Wb8,
    __hip_bfloat16* __restrict__ Wfp,
    float* __restrict__ scale_ws,
    float* __restrict__ zero_ws)
{
    const int t = threadIdx.x;
    if (blockIdx.x < TOKENS) {
        const int m = blockIdx.x;
        const float* xr = x + (size_t)m * IN_FEAT;
        const bool is64 = (int_idx_raw[1] == 0) && (int_idx_raw[3] == 0);

        float v[15];
        float mn = 1e30f, mx = -1e30f;
#pragma unroll
        for (int j = 0; j < 15; ++j) {
            int k = t + j * 256;
            int idx = is64 ? int_idx_raw[2 * k] : int_idx_raw[k];
            float f = xr[idx];
            v[j] = f;
            mn = fminf(mn, f);
            mx = fmaxf(mx, f);
        }
#pragma unroll
        for (int off = 1; off < 64; off <<= 1) {
            mn = fminf(mn, __shfl_xor(mn, off));
            mx = fmaxf(mx, __shfl_xor(mx, off));
        }
        __shared__ float smn[4], smx[4];
        int wid = t >> 6, lane = t & 63;
        if (lane == 0) { smn[wid] = mn; smx[wid] = mx; }
        __syncthreads();
        if (t == 0) {
            float rmn = fminf(fminf(smn[0], smn[1]), fminf(smn[2], smn[3]));
            float rmx = fmaxf(fmaxf(smx[0], smx[1]), fmaxf(smx[2], smx[3]));
            float sc = fmaxf((rmx - rmn) / 15.0f, 1e-8f);
            smn[0] = rmn;
            smx[0] = sc;
            scale_ws[m] = sc;
            zero_ws[m] = rmn;
        }
        __syncthreads();
        const float zero = smn[0];
        const float sc = smx[0];

        signed char* ar = Aq8 + (size_t)m * INT_FEAT;
#pragma unroll
        for (int j = 0; j < 15; ++j) {
            int k = t + j * 256;
            float q = rintf((v[j] - zero) / sc) - 8.0f;  // IEEE div+rndne == np
            q = fminf(fmaxf(q, -8.0f), 7.0f);
            ar[k] = (signed char)(int)q;                 // exact small int
        }
        int fpi = is64 ? fp_idx_raw[2 * t] : fp_idx_raw[t];
        Afp[(size_t)m * FP_FEAT + t] = __float2bfloat16(xr[fpi] / sc);
    } else {
        const int n = blockIdx.x - TOKENS;
        bool is_i32 = true;
#pragma unroll
        for (int j = 0; j < 8; ++j) {
            unsigned w = (unsigned)wpacked_raw[j];
            if (w > 0xFFu) is_i32 = false;
        }
        short* wo = (short*)(Wb8 + (size_t)n * INT_FEAT);
#pragma unroll
        for (int j = 0; j < 8; ++j) {
            int k = t + j * 256;
            if (k < PACKED_W) {
                int p = is_i32 ? wpacked_raw[(size_t)n * PACKED_W + k]
                               : ((const unsigned char*)wpacked_raw)[(size_t)n * PACKED_W + k];
                int lo = p & 15; if (lo >= 8) lo -= 16;
                int hi = (p >> 4) & 15; if (hi >= 8) hi -= 16;
                wo[k] = (short)(((unsigned char)lo) | ((unsigned short)(unsigned char)hi << 8));
            }
        }
        float wsn = wscale[n];
        Wfp[(size_t)n * FP_FEAT + t] = __float2bfloat16(fpw[(size_t)n * FP_FEAT + t] / wsn);
    }
}

// -------------------------------- GEMM 256x256, A via LDS, B direct-to-reg --
// r15: LDS-port relief. B fragments (16B/lane, 16 full 64B lines per frag,
// L2-resident panel) load straight to registers -- removes 32KB LDS B-reads
// + 16KB B DMA-writes per CU-tile (port 128->80 KB). A stays on the verified
// r12 path (DMA staging, swizzle, 0 conflicts). B double-buffered in
// statically-named reg sets bA/bB (rule 20) via unroll-2.
// vmcnt accounting (order-robust): per tile issue loadB4(vt+1) [4] +
// stageA(vt+2) [2]. One mid-tile vmcnt(6) guarantees B(vt) AND A(vt+1)
// retired under ANY intra-tile VMEM issue order (newest 6 = the current
// tile's issues), leaving B(vt+1)+A(vt+2) in flight -- counted, never 0
// until the last 2 tiles (4, then 0). Barrier per tile protects A buffers
// (4 x 16KB). K-order per acc element identical to r10-r14 -> absmax must
// stay bit-exact 0.1992188.

#define TILE_I8(VT, BUSE, BLOAD)                                               \
    {                                                                          \
        const int bufB = ((VT) & 3) << 14;                                     \
        loadB4((VT) + 1, BLOAD);                                               \
        stageA((VT) + 2, (((VT) + 2) & 3) << 14);                              \
        int32x4 aI[8];                                                         \
        _Pragma("unroll")                                                      \
        for (int mf = 0; mf < 8; ++mf)                                         \
            aI[mf] = *(const int32x4*)(lds + bufB + aOff[mf]);                 \
        asm volatile("s_waitcnt vmcnt(6)" ::: "memory");                       \
        asm volatile("s_waitcnt lgkmcnt(0)" ::: "memory");                     \
        __builtin_amdgcn_sched_barrier(0);                                     \
        __builtin_amdgcn_s_setprio(1);                                         \
        _Pragma("unroll")                                                      \
        for (int mf = 0; mf < 8; ++mf)                                         \
            _Pragma("unroll")                                                  \
            for (int nf = 0; nf < 4; ++nf)                                     \
                acc[mf][nf] = __builtin_amdgcn_mfma_i32_16x16x64_i8(           \
                    aI[mf], (BUSE)[nf], acc[mf][nf], 0, 0, 0);                 \
        __builtin_amdgcn_s_setprio(0);                                         \
        __builtin_amdgcn_sched_barrier(0);                                     \
        __builtin_amdgcn_s_barrier();                                          \
        __builtin_amdgcn_sched_barrier(0);                                     \
    }

#define TILE_FP(VT, BUSE, BLOAD, MIDSTR)                                       \
    {                                                                          \
        const int bufB = ((VT) & 3) << 14;                                     \
        if ((VT) + 1 < NT_ALL) loadB4((VT) + 1, BLOAD);                        \
        if ((VT) + 2 < NT_ALL) stageA((VT) + 2, (((VT) + 2) & 3) << 14);       \
        short8 aF[8];                                                          \
        _Pragma("unroll")                                                      \
        for (int mf = 0; mf < 8; ++mf)                                         \
            aF[mf] = *(const short8*)(lds + bufB + aOff[mf]);                  \
        asm volatile("s_waitcnt vmcnt(" MIDSTR ")" ::: "memory");              \
        asm volatile("s_waitcnt lgkmcnt(0)" ::: "memory");                     \
        __builtin_amdgcn_sched_barrier(0);                                     \
        __builtin_amdgcn_s_setprio(1);                                         \
        _Pragma("unroll")                                                      \
        for (int mf = 0; mf < 8; ++mf)                                         \
            _Pragma("unroll")                                                  \
            for (int nf = 0; nf < 4; ++nf)                                     \
                acc[mf][nf] = __builtin_bit_cast(int32x4,                      \
                    __builtin_amdgcn_mfma_f32_16x16x32_bf16(                   \
                        aF[mf], __builtin_bit_cast(short8, (BUSE)[nf]),        \
                        __builtin_bit_cast(f32x4, acc[mf][nf]), 0, 0, 0));     \
        __builtin_amdgcn_s_setprio(0);                                         \
        __builtin_amdgcn_sched_barrier(0);                                     \
        __builtin_amdgcn_s_barrier();                                          \
        __builtin_amdgcn_sched_barrier(0);                                     \
    }

__global__ __launch_bounds__(512, 2) void gemm256_i8(
    const signed char* __restrict__ Aq8,
    const __hip_bfloat16* __restrict__ Afp,
    const signed char* __restrict__ Wb8,
    const __hip_bfloat16* __restrict__ Wfp,
    const float* __restrict__ scale_ws,
    const float* __restrict__ zero_ws,
    const float* __restrict__ wscale,
    const float* __restrict__ reduced,
    const float* __restrict__ bias,
    float* __restrict__ out)
{
    __shared__ __align__(16) char lds[65536];  // 4 x 16KB, A only

    const int t = threadIdx.x;
    const int lane = t & 63, wid = t >> 6;
    const int wr = wid >> 2;                   // 0..1
    const int wc = wid & 3;                    // 0..3
    const int r16 = lane & 15;
    const int kg = lane >> 4;                  // 0..3

    // XCD-aware block swizzle (256 blocks, 8 XCDs)
    const int bid = blockIdx.x;
    const int sb = (bid & 7) * 32 + (bid >> 3);
    const int tileM = (sb >> 4) * 256;
    const int tileN = (sb & 15) * 256;

    // ---- A staging (verified r12/r14 pattern): 2 x 16B chunks per thread ---
    const int r0 = t >> 2, c0 = t & 3;
    const int sw0 = ((c0 ^ ((r0 >> 1) & 3)) << 4);
    const char* a8_0 = (const char*)Aq8 + (size_t)(tileM + r0) * INT_FEAT + sw0;
    const char* a8_1 = (const char*)Aq8 + (size_t)(tileM + 128 + r0) * INT_FEAT + sw0;
    const char* af_0 = (const char*)Afp + (size_t)(tileM + r0) * 512 + sw0;
    const char* af_1 = (const char*)Afp + (size_t)(tileM + 128 + r0) * 512 + sw0;
    const int dstA0 = t << 4;
    const int dstA1 = (512 + t) << 4;

    auto stageA = [&](int vt, int bufB) {
        const bool i8p = vt < NT_I8;
        const int ko = i8p ? vt * 64 : (vt - NT_I8) * 64;
        const char* pa0 = (i8p ? a8_0 : af_0) + ko;
        const char* pa1 = (i8p ? a8_1 : af_1) + ko;
        __builtin_amdgcn_global_load_lds(
            (const __attribute__((address_space(1))) void*)pa0,
            (__attribute__((address_space(3))) void*)(lds + bufB + dstA0), 16, 0, 0);
        __builtin_amdgcn_global_load_lds(
            (const __attribute__((address_space(1))) void*)pa1,
            (__attribute__((address_space(3))) void*)(lds + bufB + dstA1), 16, 0, 0);
    };

    // ---- B direct-to-register: lane base pointers (fragment layout) -------
    const char* bi8 = (const char*)Wb8
        + (size_t)(tileN + wc * 64 + r16) * INT_FEAT + kg * 16;
    const char* bfp = (const char*)Wfp
        + (size_t)(tileN + wc * 64 + r16) * 512 + kg * 16;

    auto loadB4 = [&](int vt, int32x4* d) {
        if (vt < NT_I8) {
            const char* p = bi8 + vt * 64;
            d[0] = *(const int32x4*)(p);
            d[1] = *(const int32x4*)(p + 16 * INT_FEAT);
            d[2] = *(const int32x4*)(p + 32 * INT_FEAT);
            d[3] = *(const int32x4*)(p + 48 * INT_FEAT);
        } else {
            const char* p = bfp + (vt - NT_I8) * 64;
            d[0] = *(const int32x4*)(p);
            d[1] = *(const int32x4*)(p + 16 * 512);
            d[2] = *(const int32x4*)(p + 32 * 512);
            d[3] = *(const int32x4*)(p + 48 * 512);
        }
    };

    // fragment read byte-offsets for A (64B rows, swizzled, 0 conflicts)
    int aOff[8];
#pragma unroll
    for (int mf = 0; mf < 8; ++mf) {
        int ra = wr * 128 + mf * 16 + r16;
        aOff[mf] = ra * 64 + ((((ra >> 1) & 3) ^ kg) << 4);
    }

    int32x4 acc[8][4];
#pragma unroll
    for (int mf = 0; mf < 8; ++mf)
#pragma unroll
        for (int nf = 0; nf < 4; ++nf)
            acc[mf][nf] = (int32x4){0, 0, 0, 0};

    int32x4 bA[4], bB[4];

    // prologue: stage A(0),A(1); load B(0); drain all (one-time vmcnt 0)
    stageA(0, 0);
    stageA(1, 16384);
    loadB4(0, bA);
    asm volatile("s_waitcnt vmcnt(0)" ::: "memory");
    __builtin_amdgcn_sched_barrier(0);
    __builtin_amdgcn_s_barrier();
    __builtin_amdgcn_sched_barrier(0);

    // ---- 60 i8 K-tiles, unroll-2 for static B reg double-buffer ----
    for (int vt = 0; vt < NT_I8; vt += 2) {
        TILE_I8(vt, bA, bB);
        TILE_I8(vt + 1, bB, bA);
    }
    // bA now holds B(60)

    // ---- exact int32 -> f32 conversion (in place, bit-pattern reuse) ----
#pragma unroll
    for (int mf = 0; mf < 8; ++mf)
#pragma unroll
        for (int nf = 0; nf < 4; ++nf) {
            int32x4 vi = acc[mf][nf];
            f32x4 vf;
#pragma unroll
            for (int i = 0; i < 4; ++i) vf[i] = (float)vi[i];
            acc[mf][nf] = __builtin_bit_cast(int32x4, vf);
        }

    // ---- 8 bf16 fp sub-tiles ----
    TILE_FP(60, bA, bB, "6");
    TILE_FP(61, bB, bA, "6");
    TILE_FP(62, bA, bB, "6");
    TILE_FP(63, bB, bA, "6");
    TILE_FP(64, bA, bB, "6");
    TILE_FP(65, bB, bA, "6");
    TILE_FP(66, bA, bB, "4");
    TILE_FP(67, bB, bA, "0");

    // epilogue: out = sc*ws*acc + (zero + 8*sc)*reduced + bias
    const int cr4 = kg * 4;
#pragma unroll
    for (int mf = 0; mf < 8; ++mf) {
#pragma unroll
        for (int nf = 0; nf < 4; ++nf) {
            int n = tileN + wc * 64 + nf * 16 + r16;
            float ws = wscale[n];
            float rd = reduced[n];
            float bs = bias[n];
            f32x4 av = __builtin_bit_cast(f32x4, acc[mf][nf]);
#pragma unroll
            for (int i = 0; i < 4; ++i) {
                int m = tileM + wr * 128 + mf * 16 + cr4 + i;
                float sc = scale_ws[m];
                float zr = zero_ws[m];
                out[(size_t)m * OUT_FEAT + n] =
                    sc * ws * av[i]
                    + (zr + sc * 8.0f) * rd + bs;
            }
        }
    }
}

// ------------------------------------------------------------------ launch ---
extern "C" void kernel_launch(void* const* d_in, const int* in_sizes, int n_in,
                              void* d_out, int out_size, void* d_ws, size_t ws_size,
                              hipStream_t stream)
{
    const void* px = 0; const void* pw = 0; const void* pfpw = 0;
    const void* pii = 0; const void* pfi = 0;
    const void* p4096[3] = {0, 0, 0}; int n4096 = 0;
    for (int i = 0; i < n_in; ++i) {
        switch (in_sizes[i]) {
            case 16777216: px = d_in[i]; break;
            case 7864320:  pw = d_in[i]; break;
            case 1048576:  pfpw = d_in[i]; break;
            case 3840:     pii = d_in[i]; break;
            case 256:      pfi = d_in[i]; break;
            case 4096:     if (n4096 < 3) p4096[n4096++] = d_in[i]; break;
            default: break;
        }
    }
    if (!px || !pw || !pfpw || !pii || !pfi || n4096 != 3) return;

    const float* x       = (const float*)px;
    const int*   wpacked = (const int*)pw;
    const float* wscale  = (const float*)p4096[0];
    const float* reduced = (const float*)p4096[1];
    const float* bias    = (const float*)p4096[2];
    const float* fpw     = (const float*)pfpw;
    const int*   int_idx = (const int*)pii;
    const int*   fp_idx  = (const int*)pfi;
    float*       out     = (float*)d_out;

    if (ws_size < (size_t)WS_NEED) return;

    char* ws = (char*)d_ws;
    signed char*    Aq8 = (signed char*)(ws + AQ8_OFF);
    signed char*    Wb8 = (signed char*)(ws + WB8_OFF);
    __hip_bfloat16* Afp = (__hip_bfloat16*)(ws + AFP_OFF);
    __hip_bfloat16* Wfp = (__hip_bfloat16*)(ws + WFP_OFF);
    float* scale_ws     = (float*)(ws + SCALE_OFF);
    float* zero_ws      = (float*)(ws + ZERO_OFF);

    prep_kernel<<<TOKENS + OUT_FEAT, 256, 0, stream>>>(
        x, int_idx, fp_idx, wpacked, fpw, wscale,
        Aq8, Afp, Wb8, Wfp, scale_ws, zero_ws);
    gemm256_i8<<<256, 512, 0, stream>>>(Aq8, Afp, Wb8, Wfp,
                                        scale_ws, zero_ws,
                                        wscale, reduced, bias, out);
}

// Round 16
// 98.180 us; speedup vs baseline: 1.3751x; 1.3751x over previous
//
#include <hip/hip_runtime.h>
#include <hip/hip_bf16.h>

#define IN_FEAT 4096
#define OUT_FEAT 4096
#define FP_FEAT 256
#define INT_FEAT 3840
#define TOKENS 4096
#define PACKED_W (INT_FEAT / 2)  // 1920

#define NT_I8 60          // int K-tiles (K=64 i8 each)
#define NT_ALL 68         // + 8 fp sub-tiles (K=32 bf16 each)

typedef __attribute__((ext_vector_type(8))) short short8;
typedef __attribute__((ext_vector_type(4))) float f32x4;
typedef __attribute__((ext_vector_type(4))) int   int32x4;

// workspace layout (bytes)
#define AQ8_OFF   0u
#define WB8_OFF   16777216u
#define AFP_OFF   33554432u
#define WFP_OFF   35651584u
#define SCALE_OFF 37748736u
#define ZERO_OFF  37765120u
#define WS_NEED   37781504u

// ------------------------------------------------- fused quantize + unpack ---
__global__ __launch_bounds__(256) void prep_kernel(
    const float* __restrict__ x,
    const int* __restrict__ int_idx_raw,
    const int* __restrict__ fp_idx_raw,
    const int* __restrict__ wpacked_raw,
    const float* __restrict__ fpw,
    const float* __restrict__ wscale,
    signed char* __restrict__ Aq8,
    __hip_bfloat16* __restrict__ Afp,
    signed char* __restrict__ Wb8,
    __hip_bfloat16* __restrict__ Wfp,
    float* __restrict__ scale_ws,
    float* __restrict__ zero_ws)
{
    const int t = threadIdx.x;
    if (blockIdx.x < TOKENS) {
        const int m = blockIdx.x;
        const float* xr = x + (size_t)m * IN_FEAT;
        const bool is64 = (int_idx_raw[1] == 0) && (int_idx_raw[3] == 0);

        float v[15];
        float mn = 1e30f, mx = -1e30f;
#pragma unroll
        for (int j = 0; j < 15; ++j) {
            int k = t + j * 256;
            int idx = is64 ? int_idx_raw[2 * k] : int_idx_raw[k];
            float f = xr[idx];
            v[j] = f;
            mn = fminf(mn, f);
            mx = fmaxf(mx, f);
        }
#pragma unroll
        for (int off = 1; off < 64; off <<= 1) {
            mn = fminf(mn, __shfl_xor(mn, off));
            mx = fmaxf(mx, __shfl_xor(mx, off));
        }
        __shared__ float smn[4], smx[4];
        int wid = t >> 6, lane = t & 63;
        if (lane == 0) { smn[wid] = mn; smx[wid] = mx; }
        __syncthreads();
        if (t == 0) {
            float rmn = fminf(fminf(smn[0], smn[1]), fminf(smn[2], smn[3]));
            float rmx = fmaxf(fmaxf(smx[0], smx[1]), fmaxf(smx[2], smx[3]));
            float sc = fmaxf((rmx - rmn) / 15.0f, 1e-8f);
            smn[0] = rmn;
            smx[0] = sc;
            scale_ws[m] = sc;
            zero_ws[m] = rmn;
        }
        __syncthreads();
        const float zero = smn[0];
        const float sc = smx[0];

        signed char* ar = Aq8 + (size_t)m * INT_FEAT;
#pragma unroll
        for (int j = 0; j < 15; ++j) {
            int k = t + j * 256;
            float q = rintf((v[j] - zero) / sc) - 8.0f;  // IEEE div+rndne == np
            q = fminf(fmaxf(q, -8.0f), 7.0f);
            ar[k] = (signed char)(int)q;                 // exact small int
        }
        int fpi = is64 ? fp_idx_raw[2 * t] : fp_idx_raw[t];
        Afp[(size_t)m * FP_FEAT + t] = __float2bfloat16(xr[fpi] / sc);
    } else {
        const int n = blockIdx.x - TOKENS;
        bool is_i32 = true;
#pragma unroll
        for (int j = 0; j < 8; ++j) {
            unsigned w = (unsigned)wpacked_raw[j];
            if (w > 0xFFu) is_i32 = false;
        }
        short* wo = (short*)(Wb8 + (size_t)n * INT_FEAT);
#pragma unroll
        for (int j = 0; j < 8; ++j) {
            int k = t + j * 256;
            if (k < PACKED_W) {
                int p = is_i32 ? wpacked_raw[(size_t)n * PACKED_W + k]
                               : ((const unsigned char*)wpacked_raw)[(size_t)n * PACKED_W + k];
                int lo = p & 15; if (lo >= 8) lo -= 16;
                int hi = (p >> 4) & 15; if (hi >= 8) hi -= 16;
                wo[k] = (short)(((unsigned char)lo) | ((unsigned short)(unsigned char)hi << 8));
            }
        }
        float wsn = wscale[n];
        Wfp[(size_t)n * FP_FEAT + t] = __float2bfloat16(fpw[(size_t)n * FP_FEAT + t] / wsn);
    }
}

// ------------------------- GEMM 256x256 i8, paired-barrier skew pipeline ----
// r16 = r12 (best, 88.8us GEMM) with the barrier interval widened to 2 tiles.
// 4 x 32KB LDS buffers, stage distance 2: pair p reads bufs {p&3,(p+1)&3},
// stages pair p+1 into bufs {(p+2)&3,(p+3)&3} -- DISJOINT regardless of
// intra-pair wave skew, so no barrier is needed between the two tiles of a
// pair. Waves skew across a ~6000cyc window: one wave's tile-(vt+1) ds_reads
// overlap another's tile-vt MFMA burst (cross-wave port/matrix overlap the
// per-tile barrier was destroying).
// Safety audit: reads of tile vt+1's buffer need ALL waves' stage(vt+1)
// complete -- staged during pair p-1, drained by each wave's own pair-end
// vmcnt(0), published by the pair-start barrier. Stage(vt+2/vt+3) targets
// bufs not read this pair (shown above). A wave's own reads are protected
// by compiler lgkm waits (plain C++ ds_reads). vmcnt(0) at pair end: issue->
// drain distance is 1.5-2 tiles (~5000cyc) >> HBM latency, so the wait is a
// cheap confirm, and next pair's reads need full drain anyway.
// Numerics: K-order per acc element identical to r10-r15 -> absmax must
// stay bit-exact 0.1992188 (race detector).

__global__ __launch_bounds__(512, 2) void gemm256_i8(
    const signed char* __restrict__ Aq8,
    const __hip_bfloat16* __restrict__ Afp,
    const signed char* __restrict__ Wb8,
    const __hip_bfloat16* __restrict__ Wfp,
    const float* __restrict__ scale_ws,
    const float* __restrict__ zero_ws,
    const float* __restrict__ wscale,
    const float* __restrict__ reduced,
    const float* __restrict__ bias,
    float* __restrict__ out)
{
    __shared__ __align__(16) char lds[131072];  // 4 x (16K A + 16K B)

    const int t = threadIdx.x;
    const int lane = t & 63, wid = t >> 6;
    const int wr = wid >> 2;                   // 0..1
    const int wc = wid & 3;                    // 0..3
    const int r16 = lane & 15;
    const int kg = lane >> 4;                  // 0..3

    // XCD-aware block swizzle (256 blocks, 8 XCDs)
    const int bid = blockIdx.x;
    const int sb = (bid & 7) * 32 + (bid >> 3);
    const int tileM = (sb >> 4) * 256;
    const int tileN = (sb & 15) * 256;

    // staging geometry: 1024 16B-chunks per operand tile, 2 per thread
    const int id0 = t, id1 = 512 + t;
    const int r0 = id0 >> 2, c0 = id0 & 3;
    const int r1 = id1 >> 2, c1 = id1 & 3;
    const int sw0 = ((c0 ^ ((r0 >> 1) & 3)) << 4);
    const int sw1 = ((c1 ^ ((r1 >> 1) & 3)) << 4);
    const char* a8_0 = (const char*)Aq8 + (size_t)(tileM + r0) * INT_FEAT + sw0;
    const char* a8_1 = (const char*)Aq8 + (size_t)(tileM + r1) * INT_FEAT + sw1;
    const char* b8_0 = (const char*)Wb8 + (size_t)(tileN + r0) * INT_FEAT + sw0;
    const char* b8_1 = (const char*)Wb8 + (size_t)(tileN + r1) * INT_FEAT + sw1;
    const char* af_0 = (const char*)Afp + (size_t)(tileM + r0) * 512 + sw0;
    const char* af_1 = (const char*)Afp + (size_t)(tileM + r1) * 512 + sw1;
    const char* bf_0 = (const char*)Wfp + (size_t)(tileN + r0) * 512 + sw0;
    const char* bf_1 = (const char*)Wfp + (size_t)(tileN + r1) * 512 + sw1;
    const int dst0 = id0 << 4, dst1 = id1 << 4;

    auto stage = [&](int vt, int bufB) {
        const bool i8p = vt < NT_I8;
        const int ko = i8p ? vt * 64 : (vt - NT_I8) * 64;
        const char* pa0 = (i8p ? a8_0 : af_0) + ko;
        const char* pa1 = (i8p ? a8_1 : af_1) + ko;
        const char* pb0 = (i8p ? b8_0 : bf_0) + ko;
        const char* pb1 = (i8p ? b8_1 : bf_1) + ko;
        __builtin_amdgcn_global_load_lds(
            (const __attribute__((address_space(1))) void*)pa0,
            (__attribute__((address_space(3))) void*)(lds + bufB + dst0), 16, 0, 0);
        __builtin_amdgcn_global_load_lds(
            (const __attribute__((address_space(1))) void*)pa1,
            (__attribute__((address_space(3))) void*)(lds + bufB + dst1), 16, 0, 0);
        __builtin_amdgcn_global_load_lds(
            (const __attribute__((address_space(1))) void*)pb0,
            (__attribute__((address_space(3))) void*)(lds + bufB + 16384 + dst0), 16, 0, 0);
        __builtin_amdgcn_global_load_lds(
            (const __attribute__((address_space(1))) void*)pb1,
            (__attribute__((address_space(3))) void*)(lds + bufB + 16384 + dst1), 16, 0, 0);
    };

    // fragment read byte-offsets (dtype-independent: 64B rows, 16B frags)
    int aOff[8], bOff[4];
#pragma unroll
    for (int mf = 0; mf < 8; ++mf) {
        int ra = wr * 128 + mf * 16 + r16;
        aOff[mf] = ra * 64 + ((((ra >> 1) & 3) ^ kg) << 4);
    }
#pragma unroll
    for (int nf = 0; nf < 4; ++nf) {
        int rb = wc * 64 + nf * 16 + r16;
        bOff[nf] = 16384 + rb * 64 + ((((rb >> 1) & 3) ^ kg) << 4);
    }

    int32x4 acc[8][4];
#pragma unroll
    for (int mf = 0; mf < 8; ++mf)
#pragma unroll
        for (int nf = 0; nf < 4; ++nf)
            acc[mf][nf] = (int32x4){0, 0, 0, 0};

    // prologue: stage pair 0 (tiles 0,1); full drain; barrier
    stage(0, 0);
    stage(1, 32768);
    asm volatile("s_waitcnt vmcnt(0)" ::: "memory");
    __builtin_amdgcn_sched_barrier(0);
    __builtin_amdgcn_s_barrier();
    __builtin_amdgcn_sched_barrier(0);

    // ---- i8 pairs: 30 pairs, 1 barrier per pair ----
#define TILE_I8_BODY(VT)                                                       \
    {                                                                          \
        const int bufB = ((VT) & 3) << 15;                                     \
        int32x4 bI[4], aI[8];                                                  \
        _Pragma("unroll")                                                      \
        for (int nf = 0; nf < 4; ++nf)                                         \
            bI[nf] = *(const int32x4*)(lds + bufB + bOff[nf]);                 \
        _Pragma("unroll")                                                      \
        for (int mf = 0; mf < 8; ++mf)                                         \
            aI[mf] = *(const int32x4*)(lds + bufB + aOff[mf]);                 \
        stage((VT) + 2, (((VT) + 2) & 3) << 15);                               \
        __builtin_amdgcn_s_setprio(1);                                         \
        _Pragma("unroll")                                                      \
        for (int mf = 0; mf < 8; ++mf)                                         \
            _Pragma("unroll")                                                  \
            for (int nf = 0; nf < 4; ++nf)                                     \
                acc[mf][nf] = __builtin_amdgcn_mfma_i32_16x16x64_i8(           \
                    aI[mf], bI[nf], acc[mf][nf], 0, 0, 0);                     \
        __builtin_amdgcn_s_setprio(0);                                         \
    }

    for (int vt = 0; vt < NT_I8; vt += 2) {
        TILE_I8_BODY(vt);          // stages vt+2 (fp-capable via stage())
        TILE_I8_BODY(vt + 1);      // stages vt+3
        asm volatile("s_waitcnt vmcnt(0)" ::: "memory");
        __builtin_amdgcn_sched_barrier(0);
        __builtin_amdgcn_s_barrier();
        __builtin_amdgcn_sched_barrier(0);
    }
#undef TILE_I8_BODY

    // ---- exact int32 -> f32 conversion (in place, bit-pattern reuse) ----
#pragma unroll
    for (int mf = 0; mf < 8; ++mf)
#pragma unroll
        for (int nf = 0; nf < 4; ++nf) {
            int32x4 vi = acc[mf][nf];
            f32x4 vf;
#pragma unroll
            for (int i = 0; i < 4; ++i) vf[i] = (float)vi[i];
            acc[mf][nf] = __builtin_bit_cast(int32x4, vf);
        }

    // ---- fp pairs: tiles 60..67, 4 pairs ----
#define TILE_FP_BODY(VT)                                                       \
    {                                                                          \
        const int bufB = ((VT) & 3) << 15;                                     \
        short8 bF[4], aF[8];                                                   \
        _Pragma("unroll")                                                      \
        for (int nf = 0; nf < 4; ++nf)                                         \
            bF[nf] = *(const short8*)(lds + bufB + bOff[nf]);                  \
        _Pragma("unroll")                                                      \
        for (int mf = 0; mf < 8; ++mf)                                         \
            aF[mf] = *(const short8*)(lds + bufB + aOff[mf]);                  \
        if ((VT) + 2 < NT_ALL)                                                 \
            stage((VT) + 2, (((VT) + 2) & 3) << 15);                           \
        __builtin_amdgcn_s_setprio(1);                                         \
        _Pragma("unroll")                                                      \
        for (int mf = 0; mf < 8; ++mf)                                         \
            _Pragma("unroll")                                                  \
            for (int nf = 0; nf < 4; ++nf)                                     \
                acc[mf][nf] = __builtin_bit_cast(int32x4,                      \
                    __builtin_amdgcn_mfma_f32_16x16x32_bf16(                   \
                        aF[mf], bF[nf],                                        \
                        __builtin_bit_cast(f32x4, acc[mf][nf]), 0, 0, 0));     \
        __builtin_amdgcn_s_setprio(0);                                         \
    }

    for (int vt = NT_I8; vt < NT_ALL; vt += 2) {
        TILE_FP_BODY(vt);
        TILE_FP_BODY(vt + 1);
        asm volatile("s_waitcnt vmcnt(0)" ::: "memory");
        __builtin_amdgcn_sched_barrier(0);
        __builtin_amdgcn_s_barrier();
        __builtin_amdgcn_sched_barrier(0);
    }
#undef TILE_FP_BODY

    // epilogue: out = sc*ws*acc + (zero + 8*sc)*reduced + bias
    const int cr4 = kg * 4;
#pragma unroll
    for (int mf = 0; mf < 8; ++mf) {
#pragma unroll
        for (int nf = 0; nf < 4; ++nf) {
            int n = tileN + wc * 64 + nf * 16 + r16;
            float ws = wscale[n];
            float rd = reduced[n];
            float bs = bias[n];
            f32x4 av = __builtin_bit_cast(f32x4, acc[mf][nf]);
#pragma unroll
            for (int i = 0; i < 4; ++i) {
                int m = tileM + wr * 128 + mf * 16 + cr4 + i;
                float sc = scale_ws[m];
                float zr = zero_ws[m];
                out[(size_t)m * OUT_FEAT + n] =
                    sc * ws * av[i]
                    + (zr + sc * 8.0f) * rd + bs;
            }
        }
    }
}

// ------------------------------------------------------------------ launch ---
extern "C" void kernel_launch(void* const* d_in, const int* in_sizes, int n_in,
                              void* d_out, int out_size, void* d_ws, size_t ws_size,
                              hipStream_t stream)
{
    const void* px = 0; const void* pw = 0; const void* pfpw = 0;
    const void* pii = 0; const void* pfi = 0;
    const void* p4096[3] = {0, 0, 0}; int n4096 = 0;
    for (int i = 0; i < n_in; ++i) {
        switch (in_sizes[i]) {
            case 16777216: px = d_in[i]; break;
            case 7864320:  pw = d_in[i]; break;
            case 1048576:  pfpw = d_in[i]; break;
            case 3840:     pii = d_in[i]; break;
            case 256:      pfi = d_in[i]; break;
            case 4096:     if (n4096 < 3) p4096[n4096++] = d_in[i]; break;
            default: break;
        }
    }
    if (!px || !pw || !pfpw || !pii || !pfi || n4096 != 3) return;

    const float* x       = (const float*)px;
    const int*   wpacked = (const int*)pw;
    const float* wscale  = (const float*)p4096[0];
    const float* reduced = (const float*)p4096[1];
    const float* bias    = (const float*)p4096[2];
    const float* fpw     = (const float*)pfpw;
    const int*   int_idx = (const int*)pii;
    const int*   fp_idx  = (const int*)pfi;
    float*       out     = (float*)d_out;

    if (ws_size < (size_t)WS_NEED) return;

    char* ws = (char*)d_ws;
    signed char*    Aq8 = (signed char*)(ws + AQ8_OFF);
    signed char*    Wb8 = (signed char*)(ws + WB8_OFF);
    __hip_bfloat16* Afp = (__hip_bfloat16*)(ws + AFP_OFF);
    __hip_bfloat16* Wfp = (__hip_bfloat16*)(ws + WFP_OFF);
    float* scale_ws     = (float*)(ws + SCALE_OFF);
    float* zero_ws      = (float*)(ws + ZERO_OFF);

    prep_kernel<<<TOKENS + OUT_FEAT, 256, 0, stream>>>(
        x, int_idx, fp_idx, wpacked, fpw, wscale,
        Aq8, Afp, Wb8, Wfp, scale_ws, zero_ws);
    gemm256_i8<<<256, 512, 0, stream>>>(Aq8, Afp, Wb8, Wfp,
                                        scale_ws, zero_ws,
                                        wscale, reduced, bias, out);
}